// Round 6
// baseline (287.870 us; speedup 1.0000x reference)
//
#include <hip/hip_runtime.h>

typedef __attribute__((ext_vector_type(8))) short short8;
typedef __attribute__((ext_vector_type(4))) float float4v;

#define D_MODEL 512
#define NUM_HEADS 8
#define DEPTH 64
#define SEQ 4096
#define BATCH 2
#define MROWS (BATCH * SEQ) // 8192
// 0.125 * log2(e): folded into Q projection so attn uses raw v_exp_f32 (exp2)
#define SCALE_Q 0.18033688011112043f

// swizzled short-index of 16B chunk c in row r of a 64-short-wide LDS tile
#define SW(r, c) (((r) * 64) + ((((c) ^ ((r) & 7))) * 8))

static __device__ __forceinline__ unsigned short f2bf(float f) {
  unsigned int u = __builtin_bit_cast(unsigned int, f);
  u += 0x7FFFu + ((u >> 16) & 1u); // RNE
  return (unsigned short)(u >> 16);
}
static __device__ __forceinline__ unsigned int pk2(float a, float b) {
  return (unsigned int)f2bf(a) | ((unsigned int)f2bf(b) << 16);
}

// ---------------- fused fp32 -> bf16 conversion (one launch) ----------------
struct CvtArgs {
  const float4v* src[7];
  uint2* dst[7];
  int n4[7];
};
__global__ __launch_bounds__(256) void cvt_all(CvtArgs a) {
  const int ti = blockIdx.y;
  const float4v* __restrict__ s = a.src[ti];
  uint2* __restrict__ d = a.dst[ti];
  const int n = a.n4[ti];
  for (int i = blockIdx.x * 256 + threadIdx.x; i < n; i += gridDim.x * 256) {
    float4v f = s[i];
    d[i] = make_uint2(pk2(f[0], f[1]), pk2(f[2], f[3]));
  }
}

// ---------------- fused Q/K/V projection GEMM (z selects tensor) ------------
// z=0: Q -> [b][h][s][d] bf16, scaled by SCALE_Q.  z=1: K -> same, unscaled.
// z=2: V -> [b][h][d][s] bf16 (LDS-transposed, coalesced stores).
struct QkvArgs {
  const void* X[3];
  const void* W[3];
  const float* bias[3];
  unsigned short* out[3];
};
template <int XFP32, int WFP32>
__global__ __launch_bounds__(256) void gemm_qkv(QkvArgs a) {
  __shared__ unsigned short As[64 * 72];
  __shared__ unsigned short Bs[64 * 72];
  const int z = blockIdx.z;
  const void* __restrict__ Xv = a.X[z];
  const void* __restrict__ Wv = a.W[z];
  const float* __restrict__ bias = a.bias[z];
  unsigned short* __restrict__ outv = a.out[z];
  const int t = threadIdx.x;
  const int w = t >> 6, l = t & 63, lq = l >> 4, lm = l & 15;
  const int mBase = blockIdx.x * 64;
  const int nBase = blockIdx.y * 64;
  float4v acc[4] = {};
  for (int kc = 0; kc < D_MODEL; kc += 64) {
    __syncthreads();
#pragma unroll
    for (int p = 0; p < 2; ++p) {
      int idx = p * 256 + t;
      int r = idx >> 3, c = (idx & 7) * 8;
      if (XFP32) {
        const float* Xf = (const float*)Xv;
        float4v f0 = *reinterpret_cast<const float4v*>(&Xf[(size_t)(mBase + r) * D_MODEL + kc + c]);
        float4v f1 = *reinterpret_cast<const float4v*>(&Xf[(size_t)(mBase + r) * D_MODEL + kc + c + 4]);
        short8 s;
#pragma unroll
        for (int j = 0; j < 4; ++j) {
          s[j] = (short)f2bf(f0[j]);
          s[4 + j] = (short)f2bf(f1[j]);
        }
        *reinterpret_cast<short8*>(&As[r * 72 + c]) = s;
      } else {
        const unsigned short* Xb = (const unsigned short*)Xv;
        *reinterpret_cast<short8*>(&As[r * 72 + c]) =
            *reinterpret_cast<const short8*>(&Xb[(size_t)(mBase + r) * D_MODEL + kc + c]);
      }
      if (WFP32) {
        const float* Wf = (const float*)Wv;
        float4v f0 = *reinterpret_cast<const float4v*>(&Wf[(size_t)(nBase + r) * D_MODEL + kc + c]);
        float4v f1 = *reinterpret_cast<const float4v*>(&Wf[(size_t)(nBase + r) * D_MODEL + kc + c + 4]);
        short8 s;
#pragma unroll
        for (int j = 0; j < 4; ++j) {
          s[j] = (short)f2bf(f0[j]);
          s[4 + j] = (short)f2bf(f1[j]);
        }
        *reinterpret_cast<short8*>(&Bs[r * 72 + c]) = s;
      } else {
        const unsigned short* Wb = (const unsigned short*)Wv;
        *reinterpret_cast<short8*>(&Bs[r * 72 + c]) =
            *reinterpret_cast<const short8*>(&Wb[(size_t)(nBase + r) * D_MODEL + kc + c]);
      }
    }
    __syncthreads();
#pragma unroll
    for (int kk = 0; kk < 64; kk += 32) {
      short8 av = *reinterpret_cast<const short8*>(&As[(w * 16 + lm) * 72 + kk + lq * 8]);
#pragma unroll
      for (int f = 0; f < 4; ++f) {
        short8 b = *reinterpret_cast<const short8*>(&Bs[(f * 16 + lm) * 72 + kk + lq * 8]);
        acc[f] = __builtin_amdgcn_mfma_f32_16x16x32_bf16(av, b, acc[f], 0, 0, 0);
      }
    }
  }
  if (z == 2) {
    // transpose 64x64 tile through LDS -> coalesced b128 global stores.
    __syncthreads(); // protect As reuse
    unsigned short* T = As;
#pragma unroll
    for (int f = 0; f < 4; ++f) {
      int dl = f * 16 + lm;
      float bv = bias[nBase + dl];
      uint2 u;
      u.x = pk2(acc[f][0] + bv, acc[f][1] + bv);
      u.y = pk2(acc[f][2] + bv, acc[f][3] + bv);
      int chunk = 2 * w + (lq >> 1);
      *reinterpret_cast<uint2*>(&T[SW(dl, chunk) + (lq & 1) * 4]) = u;
    }
    __syncthreads();
    const int bb = mBase >> 12, s0v = mBase & 4095, h = nBase >> 6;
    const size_t vbase = ((size_t)(bb * NUM_HEADS + h)) * DEPTH * SEQ;
#pragma unroll
    for (int p = 0; p < 2; ++p) {
      int idx = p * 256 + t;
      int d = idx >> 3, c = idx & 7;
      *reinterpret_cast<short8*>(&outv[vbase + (size_t)d * SEQ + s0v + c * 8]) =
          *reinterpret_cast<const short8*>(&T[SW(d, c)]);
    }
  } else {
    const float scale = (z == 0) ? SCALE_Q : 1.0f;
#pragma unroll
    for (int f = 0; f < 4; ++f) {
      int gn = nBase + f * 16 + lm;
      float bv = bias[gn];
#pragma unroll
      for (int r = 0; r < 4; ++r) {
        int gm = mBase + w * 16 + lq * 4 + r;
        float v = (acc[f][r] + bv) * scale;
        int bb = gm >> 12, s = gm & 4095;
        int h = gn >> 6, d = gn & 63;
        outv[(((size_t)(bb * NUM_HEADS + h) * SEQ + s) << 6) + d] = f2bf(v);
      }
    }
  }
}

// ---------------- output projection GEMM ------------------------------------
template <int WFP32>
__global__ __launch_bounds__(256) void gemm_out(
    const unsigned short* __restrict__ Xb, // AO bf16 [8192][512]
    const void* __restrict__ Wv,
    const float* __restrict__ bias,
    float* __restrict__ out) {
  __shared__ unsigned short As[64 * 72];
  __shared__ unsigned short Bs[64 * 72];
  const int t = threadIdx.x;
  const int w = t >> 6, l = t & 63, lq = l >> 4, lm = l & 15;
  const int mBase = blockIdx.x * 64;
  const int nBase = blockIdx.y * 64;
  float4v acc[4] = {};
  for (int kc = 0; kc < D_MODEL; kc += 64) {
    __syncthreads();
#pragma unroll
    for (int p = 0; p < 2; ++p) {
      int idx = p * 256 + t;
      int r = idx >> 3, c = (idx & 7) * 8;
      *reinterpret_cast<short8*>(&As[r * 72 + c]) =
          *reinterpret_cast<const short8*>(&Xb[(size_t)(mBase + r) * D_MODEL + kc + c]);
      if (WFP32) {
        const float* Wf = (const float*)Wv;
        float4v f0 = *reinterpret_cast<const float4v*>(&Wf[(size_t)(nBase + r) * D_MODEL + kc + c]);
        float4v f1 = *reinterpret_cast<const float4v*>(&Wf[(size_t)(nBase + r) * D_MODEL + kc + c + 4]);
        short8 s;
#pragma unroll
        for (int j = 0; j < 4; ++j) {
          s[j] = (short)f2bf(f0[j]);
          s[4 + j] = (short)f2bf(f1[j]);
        }
        *reinterpret_cast<short8*>(&Bs[r * 72 + c]) = s;
      } else {
        const unsigned short* Wb = (const unsigned short*)Wv;
        *reinterpret_cast<short8*>(&Bs[r * 72 + c]) =
            *reinterpret_cast<const short8*>(&Wb[(size_t)(nBase + r) * D_MODEL + kc + c]);
      }
    }
    __syncthreads();
#pragma unroll
    for (int kk = 0; kk < 64; kk += 32) {
      short8 av = *reinterpret_cast<const short8*>(&As[(w * 16 + lm) * 72 + kk + lq * 8]);
#pragma unroll
      for (int f = 0; f < 4; ++f) {
        short8 b = *reinterpret_cast<const short8*>(&Bs[(f * 16 + lm) * 72 + kk + lq * 8]);
        acc[f] = __builtin_amdgcn_mfma_f32_16x16x32_bf16(av, b, acc[f], 0, 0, 0);
      }
    }
  }
#pragma unroll
  for (int f = 0; f < 4; ++f) {
    int gn = nBase + f * 16 + lm;
    float bv = bias[gn];
#pragma unroll
    for (int r = 0; r < 4; ++r) {
      int gm = mBase + w * 16 + lq * 4 + r;
      out[(size_t)gm * D_MODEL + gn] = acc[f][r] + bv;
    }
  }
}

// ---------------- fused attention -------------------------------------------
// Block = 4 waves x 16 q-rows = 64 q-rows of one (b,h). K-tiles of 64.
// Double-buffered LDS + register prefetch, ONE barrier per iter.
// Q pre-scaled by 0.125*log2(e) -> p = exp2(S) = raw v_exp_f32.
__global__ __launch_bounds__(256) void attn(
    const unsigned short* __restrict__ Qh, // [bh][s][d] (pre-scaled)
    const unsigned short* __restrict__ Kh, // [bh][s][d]
    const unsigned short* __restrict__ Vt, // [bh][d][s]
    unsigned short* __restrict__ AO)       // [b][s][h*64+d] = [8192][512]
{
  __shared__ unsigned short Ksub[2][64 * 64]; // rows=k, cols=d (swizzled)
  __shared__ unsigned short Vsub[2][64 * 64]; // rows=d, cols=k (swizzled)
  __shared__ unsigned short Psub[64 * 64];    // rows=q(block-local), cols=k
  const int t = threadIdx.x;
  const int w = t >> 6; // wave 0..3
  const int l = t & 63, lq = l >> 4, lm = l & 15;
  const int bh = blockIdx.y;
  const size_t base = (size_t)bh * SEQ * DEPTH;
  const int qbase = blockIdx.x * 64 + w * 16;
  const unsigned short* __restrict__ Kp = Kh + base;
  const unsigned short* __restrict__ Vp = Vt + base;

  short8 qf[2]; // B-operand fragments for this wave's 16 q-rows
#pragma unroll
  for (int kk = 0; kk < 2; ++kk)
    qf[kk] = *reinterpret_cast<const short8*>(
        &Qh[base + (size_t)(qbase + lm) * DEPTH + kk * 32 + lq * 8]);

  float4v oacc[4] = {};
  float lsum = 0.f;
  short8 kreg[2], vreg[2];

  // preload tile 0 (512 chunks each over 256 threads)
#pragma unroll
  for (int p = 0; p < 2; ++p) {
    int idx = p * 256 + t;
    int r = idx >> 3, c = idx & 7;
    kreg[p] = *reinterpret_cast<const short8*>(&Kp[(size_t)r * DEPTH + c * 8]);
    vreg[p] = *reinterpret_cast<const short8*>(&Vp[(size_t)r * SEQ + c * 8]);
  }
#pragma unroll
  for (int p = 0; p < 2; ++p) {
    int idx = p * 256 + t;
    int r = idx >> 3, c = idx & 7;
    *reinterpret_cast<short8*>(&Ksub[0][SW(r, c)]) = kreg[p];
    *reinterpret_cast<short8*>(&Vsub[0][SW(r, c)]) = vreg[p];
  }
  __syncthreads();

  for (int it = 0; it < 64; ++it) {
    const int cur = it & 1;
    if (it < 63) {
      const int s0n = (it + 1) * 64;
#pragma unroll
      for (int p = 0; p < 2; ++p) {
        int idx = p * 256 + t;
        int r = idx >> 3, c = idx & 7;
        kreg[p] = *reinterpret_cast<const short8*>(&Kp[(size_t)(s0n + r) * DEPTH + c * 8]);
        vreg[p] = *reinterpret_cast<const short8*>(&Vp[(size_t)r * SEQ + s0n + c * 8]);
      }
    }
    // S^T = K . Q^T : lane -> S[q = lm][k = f*16 + lq*4 + r]
#pragma unroll
    for (int f = 0; f < 4; ++f) {
      float4v sacc = {};
#pragma unroll
      for (int kk = 0; kk < 2; ++kk) {
        short8 a = *reinterpret_cast<const short8*>(&Ksub[cur][SW(f * 16 + lm, kk * 4 + lq)]);
        sacc = __builtin_amdgcn_mfma_f32_16x16x32_bf16(a, qf[kk], sacc, 0, 0, 0);
      }
      float p0 = exp2f(sacc[0]);
      float p1 = exp2f(sacc[1]);
      float p2 = exp2f(sacc[2]);
      float p3 = exp2f(sacc[3]);
      lsum += (p0 + p1) + (p2 + p3);
      uint2 u;
      u.x = pk2(p0, p1);
      u.y = pk2(p2, p3);
      *reinterpret_cast<uint2*>(&Psub[SW(w * 16 + lm, 2 * f + (lq >> 1)) + (lq & 1) * 4]) = u;
    }
    // PV: O[q][d] += P[q][k] V^T[d][k]  (P rows are same-wave -> in-order)
#pragma unroll
    for (int kk = 0; kk < 2; ++kk) {
      short8 a = *reinterpret_cast<const short8*>(&Psub[SW(w * 16 + lm, kk * 4 + lq)]);
#pragma unroll
      for (int df = 0; df < 4; ++df) {
        short8 b = *reinterpret_cast<const short8*>(&Vsub[cur][SW(df * 16 + lm, kk * 4 + lq)]);
        oacc[df] = __builtin_amdgcn_mfma_f32_16x16x32_bf16(a, b, oacc[df], 0, 0, 0);
      }
    }
    if (it < 63) {
#pragma unroll
      for (int p = 0; p < 2; ++p) {
        int idx = p * 256 + t;
        int r = idx >> 3, c = idx & 7;
        *reinterpret_cast<short8*>(&Ksub[cur ^ 1][SW(r, c)]) = kreg[p];
        *reinterpret_cast<short8*>(&Vsub[cur ^ 1][SW(r, c)]) = vreg[p];
      }
    }
    __syncthreads();
  }
  // row-sum: reduce the 4 lq replicas of q-row lm
  float v = lsum;
  v += __shfl_xor(v, 16);
  v += __shfl_xor(v, 32);
  float rinv = 1.0f / v;
  const int bb = bh >> 3, h = bh & 7;
#pragma unroll
  for (int r = 0; r < 4; ++r) {
    float rq = __shfl(rinv, lq * 4 + r); // lane lq*4+r (lm=lq*4+r) holds that row's sum
    int s = qbase + lq * 4 + r;
#pragma unroll
    for (int df = 0; df < 4; ++df) {
      int d = df * 16 + lm;
      AO[((size_t)(bb * SEQ + s)) * D_MODEL + h * DEPTH + d] = f2bf(oacc[df][r] * rq);
    }
  }
}

extern "C" void kernel_launch(void* const* d_in, const int* in_sizes, int n_in,
                              void* d_out, int out_size, void* d_ws, size_t ws_size,
                              hipStream_t stream) {
  const void* q = d_in[0];
  const void* k = d_in[1];
  const void* v = d_in[2];
  const float* wq = (const float*)d_in[3];
  const float* bq = (const float*)d_in[4];
  const float* wk = (const float*)d_in[5];
  const float* bk = (const float*)d_in[6];
  const float* wv = (const float*)d_in[7];
  const float* bv = (const float*)d_in[8];
  const float* wo = (const float*)d_in[9];
  const float* bo = (const float*)d_in[10];

  const size_t HSD = (size_t)BATCH * NUM_HEADS * SEQ * DEPTH; // 4,194,304
  const size_t WSZ = (size_t)D_MODEL * D_MODEL;               // 262,144
  unsigned short* ws = (unsigned short*)d_ws;
  unsigned short* Qh = ws;
  unsigned short* Kh = Qh + HSD;
  unsigned short* Vt = Kh + HSD;
  unsigned short* AO = Vt + HSD;
  unsigned short* Wc[4] = {AO + HSD, AO + HSD + WSZ, AO + HSD + 2 * WSZ, AO + HSD + 3 * WSZ};
  unsigned short* Xc[3] = {Wc[3] + WSZ, Wc[3] + WSZ + HSD, Wc[3] + WSZ + 2 * HSD};
  const int tier = (ws_size >= (7 * HSD + 4 * WSZ) * 2) ? 1
                 : (ws_size >= (4 * HSD + 4 * WSZ) * 2) ? 2 : 3;

  const float* wptr[4] = {wq, wk, wv, wo};
  const void* xin[3] = {q, k, v};

  if (tier < 3) {
    CvtArgs ca = {};
    int ny = 0;
    if (tier == 1) {
      for (int i = 0; i < 3; ++i) {
        ca.src[ny] = (const float4v*)xin[i];
        ca.dst[ny] = (uint2*)Xc[i];
        ca.n4[ny++] = (int)(HSD / 4);
      }
    }
    for (int i = 0; i < 4; ++i) {
      ca.src[ny] = (const float4v*)wptr[i];
      ca.dst[ny] = (uint2*)Wc[i];
      ca.n4[ny++] = (int)(WSZ / 4);
    }
    cvt_all<<<dim3(512, ny), 256, 0, stream>>>(ca);
  }

  QkvArgs qa;
  qa.bias[0] = bq; qa.bias[1] = bk; qa.bias[2] = bv;
  qa.out[0] = Qh; qa.out[1] = Kh; qa.out[2] = Vt;
  dim3 gGrid(MROWS / 64, D_MODEL / 64, 3); // 128 x 8 x 3
  if (tier == 1) {
    for (int i = 0; i < 3; ++i) { qa.X[i] = Xc[i]; qa.W[i] = Wc[i]; }
    gemm_qkv<0, 0><<<gGrid, 256, 0, stream>>>(qa);
  } else if (tier == 2) {
    for (int i = 0; i < 3; ++i) { qa.X[i] = xin[i]; qa.W[i] = Wc[i]; }
    gemm_qkv<1, 0><<<gGrid, 256, 0, stream>>>(qa);
  } else {
    for (int i = 0; i < 3; ++i) { qa.X[i] = xin[i]; qa.W[i] = wptr[i]; }
    gemm_qkv<1, 1><<<gGrid, 256, 0, stream>>>(qa);
  }

  attn<<<dim3(SEQ / 64, BATCH * NUM_HEADS), 256, 0, stream>>>(Qh, Kh, Vt, AO);

  dim3 oGrid(MROWS / 64, D_MODEL / 64);
  if (tier < 3)
    gemm_out<0><<<oGrid, 256, 0, stream>>>(AO, Wc[3], bo, (float*)d_out);
  else
    gemm_out<1><<<oGrid, 256, 0, stream>>>(AO, wo, bo, (float*)d_out);
}

// Round 7
// 243.849 us; speedup vs baseline: 1.1805x; 1.1805x over previous
//
#include <hip/hip_runtime.h>

typedef __attribute__((ext_vector_type(8))) short short8;
typedef __attribute__((ext_vector_type(4))) float float4v;

#define D_MODEL 512
#define NUM_HEADS 8
#define DEPTH 64
#define SEQ 4096
#define BATCH 2
#define MROWS 8192
// 0.125 * log2(e): folded into Q projection so attn uses raw v_exp_f32 (exp2)
#define SCALE_Q 0.18033688011112043f

// swizzled short-index of 16B chunk c in row r of a 64-short-wide LDS tile
#define SW(r, c) (((r) * 64) + ((((c) ^ ((r) & 7))) * 8))
// 128-short-wide variant
#define SW128(n, c) (((n) * 128) + ((((c) ^ ((n) & 15))) * 8))

static __device__ __forceinline__ unsigned short f2bf(float f) {
  unsigned int u = __builtin_bit_cast(unsigned int, f);
  u += 0x7FFFu + ((u >> 16) & 1u); // RNE
  return (unsigned short)(u >> 16);
}
static __device__ __forceinline__ unsigned int pk2(float a, float b) {
  return (unsigned int)f2bf(a) | ((unsigned int)f2bf(b) << 16);
}
// fast pack: round-half-up (RNE except exact ties) + single v_perm_b32
static __device__ __forceinline__ unsigned int pk2f(float a, float b) {
  unsigned int ua = __builtin_bit_cast(unsigned int, a) + 0x8000u;
  unsigned int ub = __builtin_bit_cast(unsigned int, b) + 0x8000u;
  return __builtin_amdgcn_perm(ub, ua, 0x07060302u); // [b.3 b.2 a.3 a.2]
}

// ---------------- fused fp32 -> bf16 conversion (one launch) ----------------
struct CvtArgs {
  const float4v* src[7];
  uint2* dst[7];
  int n4[7];
};
__global__ __launch_bounds__(256) void cvt_all(CvtArgs a) {
  const int ti = blockIdx.y;
  const float4v* __restrict__ s = a.src[ti];
  uint2* __restrict__ d = a.dst[ti];
  const int n = a.n4[ti];
  for (int i = blockIdx.x * 256 + threadIdx.x; i < n; i += gridDim.x * 256) {
    float4v f = s[i];
    d[i] = make_uint2(pk2(f[0], f[1]), pk2(f[2], f[3]));
  }
}

// ---------------- 128x128-tile QKV projection (bf16 in, z selects) ----------
// z=0: Q -> [b][h][s][d] bf16 scaled by SCALE_Q; z=1: K same unscaled;
// z=2: V -> [b][h][d][s] bf16 via LDS transpose.
struct QkvArgs {
  const unsigned short* X[3];
  const unsigned short* W[3];
  const float* bias[3];
  unsigned short* out[3];
};
__global__ __launch_bounds__(256) void gemm128_qkv(QkvArgs a) {
  __shared__ unsigned short smem[2 * 128 * 64];
  unsigned short* As = smem;
  unsigned short* Bs = smem + 128 * 64;
  const int z = blockIdx.z;
  const unsigned short* __restrict__ X = a.X[z];
  const unsigned short* __restrict__ W = a.W[z];
  const float* __restrict__ bias = a.bias[z];
  unsigned short* __restrict__ out = a.out[z];
  const int t = threadIdx.x;
  const int w = t >> 6, l = t & 63, lq = l >> 4, lm = l & 15;
  const int mq = (w & 1) * 64, nq = (w >> 1) * 64;
  const int mBase = blockIdx.x * 128, nBase = blockIdx.y * 128;
  float4v acc[4][4] = {};
  for (int kc = 0; kc < D_MODEL; kc += 64) {
    __syncthreads();
#pragma unroll
    for (int p = 0; p < 4; ++p) {
      int i = p * 256 + t, r = i >> 3, c = i & 7;
      *(short8*)&As[SW(r, c)] = *(const short8*)&X[(size_t)(mBase + r) * D_MODEL + kc + c * 8];
      *(short8*)&Bs[SW(r, c)] = *(const short8*)&W[(size_t)(nBase + r) * D_MODEL + kc + c * 8];
    }
    __syncthreads();
#pragma unroll
    for (int kk = 0; kk < 2; ++kk) {
      short8 av[4];
#pragma unroll
      for (int fm = 0; fm < 4; ++fm)
        av[fm] = *(const short8*)&As[SW(mq + fm * 16 + lm, kk * 4 + lq)];
#pragma unroll
      for (int fn = 0; fn < 4; ++fn) {
        short8 bv = *(const short8*)&Bs[SW(nq + fn * 16 + lm, kk * 4 + lq)];
#pragma unroll
        for (int fm = 0; fm < 4; ++fm)
          acc[fm][fn] = __builtin_amdgcn_mfma_f32_16x16x32_bf16(av[fm], bv, acc[fm][fn], 0, 0, 0);
      }
    }
  }
  if (z == 2) {
    __syncthreads(); // protect As/Bs reuse
    unsigned short* T = smem; // 128 x 128 shorts (= As+Bs)
#pragma unroll
    for (int fn = 0; fn < 4; ++fn) {
      int n = nq + fn * 16 + lm;
      float bv = bias[nBase + n];
#pragma unroll
      for (int fm = 0; fm < 4; ++fm) {
        int m0 = mq + fm * 16 + lq * 4;
        uint2 u;
        u.x = pk2(acc[fm][fn][0] + bv, acc[fm][fn][1] + bv);
        u.y = pk2(acc[fm][fn][2] + bv, acc[fm][fn][3] + bv);
        *(uint2*)&T[SW128(n, m0 >> 3) + (lq & 1) * 4] = u;
      }
    }
    __syncthreads();
    const int bb = mBase >> 12, s0 = mBase & 4095;
#pragma unroll
    for (int p = 0; p < 8; ++p) {
      int i = p * 256 + t, n = i >> 4, cm = i & 15;
      int gn = nBase + n, h = gn >> 6, d = gn & 63;
      *(short8*)&out[(((size_t)(bb * NUM_HEADS + h) * DEPTH + d) << 12) + s0 + cm * 8] =
          *(const short8*)&T[SW128(n, cm)];
    }
  } else {
    const float scale = (z == 0) ? SCALE_Q : 1.0f;
#pragma unroll
    for (int fn = 0; fn < 4; ++fn) {
      int gn = nBase + nq + fn * 16 + lm;
      float bv = bias[gn];
      int h = gn >> 6, d = gn & 63;
#pragma unroll
      for (int fm = 0; fm < 4; ++fm) {
#pragma unroll
        for (int r = 0; r < 4; ++r) {
          int gm = mBase + mq + fm * 16 + lq * 4 + r;
          int bb = gm >> 12, s = gm & 4095;
          out[(((size_t)(bb * NUM_HEADS + h) * SEQ + s) << 6) + d] =
              f2bf((acc[fm][fn][r] + bv) * scale);
        }
      }
    }
  }
}

// ---------------- 128x128-tile output projection (bf16 in, fp32 out) --------
__global__ __launch_bounds__(256) void gemm128_out(
    const unsigned short* __restrict__ X, const unsigned short* __restrict__ W,
    const float* __restrict__ bias, float* __restrict__ out) {
  __shared__ unsigned short smem[2 * 128 * 64];
  unsigned short* As = smem;
  unsigned short* Bs = smem + 128 * 64;
  const int t = threadIdx.x;
  const int w = t >> 6, l = t & 63, lq = l >> 4, lm = l & 15;
  const int mq = (w & 1) * 64, nq = (w >> 1) * 64;
  const int mBase = blockIdx.x * 128, nBase = blockIdx.y * 128;
  float4v acc[4][4] = {};
  for (int kc = 0; kc < D_MODEL; kc += 64) {
    __syncthreads();
#pragma unroll
    for (int p = 0; p < 4; ++p) {
      int i = p * 256 + t, r = i >> 3, c = i & 7;
      *(short8*)&As[SW(r, c)] = *(const short8*)&X[(size_t)(mBase + r) * D_MODEL + kc + c * 8];
      *(short8*)&Bs[SW(r, c)] = *(const short8*)&W[(size_t)(nBase + r) * D_MODEL + kc + c * 8];
    }
    __syncthreads();
#pragma unroll
    for (int kk = 0; kk < 2; ++kk) {
      short8 av[4];
#pragma unroll
      for (int fm = 0; fm < 4; ++fm)
        av[fm] = *(const short8*)&As[SW(mq + fm * 16 + lm, kk * 4 + lq)];
#pragma unroll
      for (int fn = 0; fn < 4; ++fn) {
        short8 bv = *(const short8*)&Bs[SW(nq + fn * 16 + lm, kk * 4 + lq)];
#pragma unroll
        for (int fm = 0; fm < 4; ++fm)
          acc[fm][fn] = __builtin_amdgcn_mfma_f32_16x16x32_bf16(av[fm], bv, acc[fm][fn], 0, 0, 0);
      }
    }
  }
#pragma unroll
  for (int fn = 0; fn < 4; ++fn) {
    int gn = nBase + nq + fn * 16 + lm;
    float bv = bias[gn];
#pragma unroll
    for (int fm = 0; fm < 4; ++fm) {
#pragma unroll
      for (int r = 0; r < 4; ++r) {
        int gm = mBase + mq + fm * 16 + lq * 4 + r;
        out[(size_t)gm * D_MODEL + gn] = acc[fm][fn][r] + bv;
      }
    }
  }
}

// ---------------- fallback 64-tile QKV (fp32 X and/or W) --------------------
struct QkvArgsF {
  const void* X[3];
  const void* W[3];
  const float* bias[3];
  unsigned short* out[3];
};
template <int XFP32, int WFP32>
__global__ __launch_bounds__(256) void gemm_qkv(QkvArgsF a) {
  __shared__ unsigned short As[64 * 72];
  __shared__ unsigned short Bs[64 * 72];
  const int z = blockIdx.z;
  const void* __restrict__ Xv = a.X[z];
  const void* __restrict__ Wv = a.W[z];
  const float* __restrict__ bias = a.bias[z];
  unsigned short* __restrict__ outv = a.out[z];
  const int t = threadIdx.x;
  const int w = t >> 6, l = t & 63, lq = l >> 4, lm = l & 15;
  const int mBase = blockIdx.x * 64;
  const int nBase = blockIdx.y * 64;
  float4v acc[4] = {};
  for (int kc = 0; kc < D_MODEL; kc += 64) {
    __syncthreads();
#pragma unroll
    for (int p = 0; p < 2; ++p) {
      int idx = p * 256 + t;
      int r = idx >> 3, c = (idx & 7) * 8;
      if (XFP32) {
        const float* Xf = (const float*)Xv;
        float4v f0 = *(const float4v*)&Xf[(size_t)(mBase + r) * D_MODEL + kc + c];
        float4v f1 = *(const float4v*)&Xf[(size_t)(mBase + r) * D_MODEL + kc + c + 4];
        short8 s;
#pragma unroll
        for (int j = 0; j < 4; ++j) { s[j] = (short)f2bf(f0[j]); s[4 + j] = (short)f2bf(f1[j]); }
        *(short8*)&As[r * 72 + c] = s;
      } else {
        *(short8*)&As[r * 72 + c] =
            *(const short8*)&((const unsigned short*)Xv)[(size_t)(mBase + r) * D_MODEL + kc + c];
      }
      if (WFP32) {
        const float* Wf = (const float*)Wv;
        float4v f0 = *(const float4v*)&Wf[(size_t)(nBase + r) * D_MODEL + kc + c];
        float4v f1 = *(const float4v*)&Wf[(size_t)(nBase + r) * D_MODEL + kc + c + 4];
        short8 s;
#pragma unroll
        for (int j = 0; j < 4; ++j) { s[j] = (short)f2bf(f0[j]); s[4 + j] = (short)f2bf(f1[j]); }
        *(short8*)&Bs[r * 72 + c] = s;
      } else {
        *(short8*)&Bs[r * 72 + c] =
            *(const short8*)&((const unsigned short*)Wv)[(size_t)(nBase + r) * D_MODEL + kc + c];
      }
    }
    __syncthreads();
#pragma unroll
    for (int kk = 0; kk < 64; kk += 32) {
      short8 av = *(const short8*)&As[(w * 16 + lm) * 72 + kk + lq * 8];
#pragma unroll
      for (int f = 0; f < 4; ++f) {
        short8 b = *(const short8*)&Bs[(f * 16 + lm) * 72 + kk + lq * 8];
        acc[f] = __builtin_amdgcn_mfma_f32_16x16x32_bf16(av, b, acc[f], 0, 0, 0);
      }
    }
  }
  if (z == 2) {
    __syncthreads();
    unsigned short* T = As;
#pragma unroll
    for (int f = 0; f < 4; ++f) {
      int dl = f * 16 + lm;
      float bv = bias[nBase + dl];
      uint2 u;
      u.x = pk2(acc[f][0] + bv, acc[f][1] + bv);
      u.y = pk2(acc[f][2] + bv, acc[f][3] + bv);
      int chunk = 2 * w + (lq >> 1);
      *(uint2*)&T[SW(dl, chunk) + (lq & 1) * 4] = u;
    }
    __syncthreads();
    const int bb = mBase >> 12, s0v = mBase & 4095, h = nBase >> 6;
    const size_t vbase = ((size_t)(bb * NUM_HEADS + h)) * DEPTH * SEQ;
#pragma unroll
    for (int p = 0; p < 2; ++p) {
      int idx = p * 256 + t;
      int d = idx >> 3, c = idx & 7;
      *(short8*)&outv[vbase + (size_t)d * SEQ + s0v + c * 8] = *(const short8*)&T[SW(d, c)];
    }
  } else {
    const float scale = (z == 0) ? SCALE_Q : 1.0f;
#pragma unroll
    for (int f = 0; f < 4; ++f) {
      int gn = nBase + f * 16 + lm;
      float bv = bias[gn];
#pragma unroll
      for (int r = 0; r < 4; ++r) {
        int gm = mBase + w * 16 + lq * 4 + r;
        float v = (acc[f][r] + bv) * scale;
        int bb = gm >> 12, s = gm & 4095;
        int h = gn >> 6, d = gn & 63;
        outv[(((size_t)(bb * NUM_HEADS + h) * SEQ + s) << 6) + d] = f2bf(v);
      }
    }
  }
}

// ---------------- fallback 64-tile output projection (fp32 W) ---------------
__global__ __launch_bounds__(256) void gemm_out_f(
    const unsigned short* __restrict__ Xb, const float* __restrict__ Wf,
    const float* __restrict__ bias, float* __restrict__ out) {
  __shared__ unsigned short As[64 * 72];
  __shared__ unsigned short Bs[64 * 72];
  const int t = threadIdx.x;
  const int w = t >> 6, l = t & 63, lq = l >> 4, lm = l & 15;
  const int mBase = blockIdx.x * 64;
  const int nBase = blockIdx.y * 64;
  float4v acc[4] = {};
  for (int kc = 0; kc < D_MODEL; kc += 64) {
    __syncthreads();
#pragma unroll
    for (int p = 0; p < 2; ++p) {
      int idx = p * 256 + t;
      int r = idx >> 3, c = (idx & 7) * 8;
      *(short8*)&As[r * 72 + c] =
          *(const short8*)&Xb[(size_t)(mBase + r) * D_MODEL + kc + c];
      float4v f0 = *(const float4v*)&Wf[(size_t)(nBase + r) * D_MODEL + kc + c];
      float4v f1 = *(const float4v*)&Wf[(size_t)(nBase + r) * D_MODEL + kc + c + 4];
      short8 s;
#pragma unroll
      for (int j = 0; j < 4; ++j) { s[j] = (short)f2bf(f0[j]); s[4 + j] = (short)f2bf(f1[j]); }
      *(short8*)&Bs[r * 72 + c] = s;
    }
    __syncthreads();
#pragma unroll
    for (int kk = 0; kk < 64; kk += 32) {
      short8 av = *(const short8*)&As[(w * 16 + lm) * 72 + kk + lq * 8];
#pragma unroll
      for (int f = 0; f < 4; ++f) {
        short8 b = *(const short8*)&Bs[(f * 16 + lm) * 72 + kk + lq * 8];
        acc[f] = __builtin_amdgcn_mfma_f32_16x16x32_bf16(av, b, acc[f], 0, 0, 0);
      }
    }
  }
#pragma unroll
  for (int f = 0; f < 4; ++f) {
    int gn = nBase + f * 16 + lm;
    float bv = bias[gn];
#pragma unroll
    for (int r = 0; r < 4; ++r) {
      int gm = mBase + w * 16 + lq * 4 + r;
      out[(size_t)gm * D_MODEL + gn] = acc[f][r] + bv;
    }
  }
}

// ---------------- fused attention -------------------------------------------
// Block = 4 waves x 32 q-rows = 128 q-rows of one (b,h). K-tiles of 64.
// Double-buffered LDS + register prefetch, ONE barrier per iter.
// Q pre-scaled by 0.125*log2(e) -> p = exp2(S). Denominator via ones-MFMA.
__global__ __launch_bounds__(256) void attn(
    const unsigned short* __restrict__ Qh, // [bh][s][d] (pre-scaled)
    const unsigned short* __restrict__ Kh, // [bh][s][d]
    const unsigned short* __restrict__ Vt, // [bh][d][s]
    unsigned short* __restrict__ AO)       // [b][s][h*64+d] = [8192][512]
{
  __shared__ unsigned short Ksub[2][64 * 64]; // rows=k, cols=d (swizzled)
  __shared__ unsigned short Vsub[2][64 * 64]; // rows=d, cols=k (swizzled)
  __shared__ unsigned short Psub[128 * 64];   // rows=q(block-local), cols=k
  const int t = threadIdx.x;
  const int w = t >> 6; // wave 0..3
  const int l = t & 63, lq = l >> 4, lm = l & 15;
  const int bh = blockIdx.y;
  const size_t base = (size_t)bh * SEQ * DEPTH;
  const int qbase = blockIdx.x * 128 + w * 32;
  const unsigned short* __restrict__ Kp = Kh + base;
  const unsigned short* __restrict__ Vp = Vt + base;

  short8 qf[2][2]; // [qblock][kk] B-operand fragments held in registers
#pragma unroll
  for (int qb = 0; qb < 2; ++qb)
#pragma unroll
    for (int kk = 0; kk < 2; ++kk)
      qf[qb][kk] = *(const short8*)&Qh[base + (size_t)(qbase + qb * 16 + lm) * DEPTH + kk * 32 + lq * 8];

  short8 ones;
#pragma unroll
  for (int j = 0; j < 8; ++j) ones[j] = (short)0x3F80; // bf16 1.0

  float4v oacc[2][4] = {};
  float4v sumacc[2] = {};
  short8 kreg[2], vreg[2];

  // preload tile 0 (512 chunks each over 256 threads)
#pragma unroll
  for (int p = 0; p < 2; ++p) {
    int i = p * 256 + t, r = i >> 3, c = i & 7;
    kreg[p] = *(const short8*)&Kp[(size_t)r * DEPTH + c * 8];
    vreg[p] = *(const short8*)&Vp[(size_t)r * SEQ + c * 8];
  }
#pragma unroll
  for (int p = 0; p < 2; ++p) {
    int i = p * 256 + t, r = i >> 3, c = i & 7;
    *(short8*)&Ksub[0][SW(r, c)] = kreg[p];
    *(short8*)&Vsub[0][SW(r, c)] = vreg[p];
  }
  __syncthreads();

  for (int it = 0; it < 64; ++it) {
    const int cur = it & 1;
    if (it < 63) {
      const int s0n = (it + 1) * 64;
#pragma unroll
      for (int p = 0; p < 2; ++p) {
        int i = p * 256 + t, r = i >> 3, c = i & 7;
        kreg[p] = *(const short8*)&Kp[(size_t)(s0n + r) * DEPTH + c * 8];
        vreg[p] = *(const short8*)&Vp[(size_t)r * SEQ + s0n + c * 8];
      }
    }
    // S^T = K . Q^T : lane -> S[q = qb*16+lm][k = f*16 + lq*4 + r]
#pragma unroll
    for (int f = 0; f < 4; ++f) {
      float4v sacc[2] = {};
#pragma unroll
      for (int kk = 0; kk < 2; ++kk) {
        short8 a = *(const short8*)&Ksub[cur][SW(f * 16 + lm, kk * 4 + lq)];
        sacc[0] = __builtin_amdgcn_mfma_f32_16x16x32_bf16(a, qf[0][kk], sacc[0], 0, 0, 0);
        sacc[1] = __builtin_amdgcn_mfma_f32_16x16x32_bf16(a, qf[1][kk], sacc[1], 0, 0, 0);
      }
#pragma unroll
      for (int qb = 0; qb < 2; ++qb) {
        uint2 u;
        u.x = pk2f(__builtin_amdgcn_exp2f(sacc[qb][0]), __builtin_amdgcn_exp2f(sacc[qb][1]));
        u.y = pk2f(__builtin_amdgcn_exp2f(sacc[qb][2]), __builtin_amdgcn_exp2f(sacc[qb][3]));
        *(uint2*)&Psub[SW(w * 32 + qb * 16 + lm, 2 * f + (lq >> 1)) + (lq & 1) * 4] = u;
      }
    }
    // PV: O[q][d] += P[q][k] V^T[d][k]; denominator via B=ones MFMA.
#pragma unroll
    for (int kk = 0; kk < 2; ++kk) {
      short8 a0 = *(const short8*)&Psub[SW(w * 32 + lm, kk * 4 + lq)];
      short8 a1 = *(const short8*)&Psub[SW(w * 32 + 16 + lm, kk * 4 + lq)];
      sumacc[0] = __builtin_amdgcn_mfma_f32_16x16x32_bf16(a0, ones, sumacc[0], 0, 0, 0);
      sumacc[1] = __builtin_amdgcn_mfma_f32_16x16x32_bf16(a1, ones, sumacc[1], 0, 0, 0);
#pragma unroll
      for (int df = 0; df < 4; ++df) {
        short8 b = *(const short8*)&Vsub[cur][SW(df * 16 + lm, kk * 4 + lq)];
        oacc[0][df] = __builtin_amdgcn_mfma_f32_16x16x32_bf16(a0, b, oacc[0][df], 0, 0, 0);
        oacc[1][df] = __builtin_amdgcn_mfma_f32_16x16x32_bf16(a1, b, oacc[1][df], 0, 0, 0);
      }
    }
    if (it < 63) {
#pragma unroll
      for (int p = 0; p < 2; ++p) {
        int i = p * 256 + t, r = i >> 3, c = i & 7;
        *(short8*)&Ksub[cur ^ 1][SW(r, c)] = kreg[p];
        *(short8*)&Vsub[cur ^ 1][SW(r, c)] = vreg[p];
      }
    }
    __syncthreads();
  }
  // sumacc[qb][r] = rowsum(q = qbase + qb*16 + lq*4 + r) — same layout as oacc.
  const int bb = bh >> 3, h = bh & 7;
#pragma unroll
  for (int qb = 0; qb < 2; ++qb) {
#pragma unroll
    for (int r = 0; r < 4; ++r) {
      float rinv = 1.0f / sumacc[qb][r];
      int s = qbase + qb * 16 + lq * 4 + r;
#pragma unroll
      for (int df = 0; df < 4; ++df) {
        int d = df * 16 + lm;
        AO[((size_t)(bb * SEQ + s)) * D_MODEL + h * DEPTH + d] = f2bf(oacc[qb][df][r] * rinv);
      }
    }
  }
}

extern "C" void kernel_launch(void* const* d_in, const int* in_sizes, int n_in,
                              void* d_out, int out_size, void* d_ws, size_t ws_size,
                              hipStream_t stream) {
  const void* q = d_in[0];
  const void* k = d_in[1];
  const void* v = d_in[2];
  const float* wq = (const float*)d_in[3];
  const float* bq = (const float*)d_in[4];
  const float* wk = (const float*)d_in[5];
  const float* bk = (const float*)d_in[6];
  const float* wv = (const float*)d_in[7];
  const float* bv = (const float*)d_in[8];
  const float* wo = (const float*)d_in[9];
  const float* bo = (const float*)d_in[10];

  const size_t HSD = (size_t)BATCH * NUM_HEADS * SEQ * DEPTH; // 4,194,304
  const size_t WSZ = (size_t)D_MODEL * D_MODEL;               // 262,144
  unsigned short* ws = (unsigned short*)d_ws;
  unsigned short* Qh = ws;
  unsigned short* Kh = Qh + HSD;
  unsigned short* Vt = Kh + HSD;
  unsigned short* AO = Vt + HSD;
  unsigned short* Wc[4] = {AO + HSD, AO + HSD + WSZ, AO + HSD + 2 * WSZ, AO + HSD + 3 * WSZ};
  unsigned short* Xc[3] = {Wc[3] + WSZ, Wc[3] + WSZ + HSD, Wc[3] + WSZ + 2 * HSD};
  const int tier = (ws_size >= (7 * HSD + 4 * WSZ) * 2) ? 1
                 : (ws_size >= (4 * HSD + 4 * WSZ) * 2) ? 2 : 3;

  const float* wptr[4] = {wq, wk, wv, wo};
  const void* xin[3] = {q, k, v};

  if (tier < 3) {
    CvtArgs ca = {};
    int ny = 0;
    if (tier == 1) {
      for (int i = 0; i < 3; ++i) {
        ca.src[ny] = (const float4v*)xin[i];
        ca.dst[ny] = (uint2*)Xc[i];
        ca.n4[ny++] = (int)(HSD / 4);
      }
    }
    for (int i = 0; i < 4; ++i) {
      ca.src[ny] = (const float4v*)wptr[i];
      ca.dst[ny] = (uint2*)Wc[i];
      ca.n4[ny++] = (int)(WSZ / 4);
    }
    cvt_all<<<dim3(512, ny), 256, 0, stream>>>(ca);
  }

  if (tier == 1) {
    QkvArgs qa;
    for (int i = 0; i < 3; ++i) { qa.X[i] = Xc[i]; qa.W[i] = Wc[i]; }
    qa.bias[0] = bq; qa.bias[1] = bk; qa.bias[2] = bv;
    qa.out[0] = Qh; qa.out[1] = Kh; qa.out[2] = Vt;
    gemm128_qkv<<<dim3(MROWS / 128, D_MODEL / 128, 3), 256, 0, stream>>>(qa);
  } else {
    QkvArgsF qa;
    for (int i = 0; i < 3; ++i) qa.X[i] = xin[i];
    qa.bias[0] = bq; qa.bias[1] = bk; qa.bias[2] = bv;
    qa.out[0] = Qh; qa.out[1] = Kh; qa.out[2] = Vt;
    dim3 g(MROWS / 64, D_MODEL / 64, 3);
    if (tier == 2) {
      for (int i = 0; i < 3; ++i) qa.W[i] = Wc[i];
      gemm_qkv<1, 0><<<g, 256, 0, stream>>>(qa);
    } else {
      for (int i = 0; i < 3; ++i) qa.W[i] = wptr[i];
      gemm_qkv<1, 1><<<g, 256, 0, stream>>>(qa);
    }
  }

  attn<<<dim3(SEQ / 128, BATCH * NUM_HEADS), 256, 0, stream>>>(Qh, Kh, Vt, AO);

  if (tier < 3)
    gemm128_out<<<dim3(MROWS / 128, D_MODEL / 128), 256, 0, stream>>>(AO, Wc[3], bo, (float*)d_out);
  else
    gemm_out_f<<<dim3(MROWS / 64, D_MODEL / 64), 256, 0, stream>>>(AO, wo, bo, (float*)d_out);
}